// Round 8
// baseline (1390.082 us; speedup 1.0000x reference)
//
#include <hip/hip_runtime.h>

#define NN 262144
#define HH 512
#define CC 32
#define MOMF 0.99f

// ws layout (float offsets). Total 311808 floats = 1.22 MB (< R2-proven 1.84 MB).
#define WS_SUMS   0         // 8 x 16384 partial sums
#define WS_COUNTS 131072    // 8 x 32 partial counts
#define WS_UPD    131328
#define WS_KBUF   147712
#define WS_VBUF   164096
#define WS_SB     180480
#define WS_MT     180736    // ushort[256*512] (bf16)
#define WS_PT     246272    // ushort[512*256] (bf16)

typedef __attribute__((ext_vector_type(8))) short s8v;
typedef __attribute__((ext_vector_type(4))) float f4v;
typedef __attribute__((ext_vector_type(4))) unsigned int u4v;

static __device__ __forceinline__ unsigned short f2bf(float f) {
  unsigned int u = __float_as_uint(f);
  u += 0x7FFFu + ((u >> 16) & 1u);   // round-to-nearest-even
  return (unsigned short)(u >> 16);
}
static __device__ __forceinline__ unsigned int pk2bf(float a, float b) {
  return (unsigned int)f2bf(a) | ((unsigned int)f2bf(b) << 16);
}

// ---------------------------------------------------------------------------
// Kernel 1 (fused k-means step, MFMA assignment) — R7 structure with:
//  * phase A: 2-stage load pipeline (4-kk chunks), same MFMA order (bit-exact)
//  * phase B: 2-deep row prefetch
//  * flush: 8 partial global buffers (blockIdx&7) + rotated start
// ---------------------------------------------------------------------------
__global__ __launch_bounds__(512, 4) void k_km(const float* __restrict__ x,
                                               const float* __restrict__ cent,
                                               float* __restrict__ gsums,
                                               float* __restrict__ gcounts) {
  __shared__ __align__(16) unsigned char smem[66304];
  unsigned short* clbf = (unsigned short*)smem;        // [32][520] bf16
  float* scratch = (float*)(smem + 40960);             // setup only
  float* buf = (float*)smem;                           // phase B sums [32][512]
  float* cnS = (float*)(smem + 65536);                 // 32 floats
  unsigned char* sa = smem + 65664;                    // 512 assignments
  float* lc = (float*)(smem + 66176);                  // 32 counts

  const int tid = threadIdx.x;
  const int w = tid >> 6, l = tid & 63;
  const int l16 = l & 15, g = l >> 4;

  // ---- setup: stage cent bf16 + per-thread partial ||c||^2 ----
  {
    const int r = tid >> 4, colbase = (tid & 15) * 32;
#pragma unroll
    for (int q = 0; q < 4; ++q) {
      float4 a = *(const float4*)&cent[r * HH + colbase + q * 8];
      float4 b = *(const float4*)&cent[r * HH + colbase + q * 8 + 4];
      u4v p;
      p[0] = pk2bf(a.x, a.y); p[1] = pk2bf(a.z, a.w);
      p[2] = pk2bf(b.x, b.y); p[3] = pk2bf(b.z, b.w);
      *(u4v*)((unsigned char*)clbf + r * 1040 + (colbase + q * 8) * 2) = p;
    }
    const int c = tid >> 4, kk = tid & 15;
    float p = 0.f;
    for (int m = 0; m < 32; ++m) { float v = cent[c * HH + kk + 16 * m]; p += v * v; }
    scratch[tid] = p;
  }
  __syncthreads();
  if (tid < CC) {
    float s = 0.f;
    for (int m = 0; m < 16; ++m) s += scratch[tid * 16 + m];
    cnS[tid] = s;
  }
  __syncthreads();

  // hoist this lane's 8 cn values (c = tc*16 + 4g + r)
  float cnr[8];
#pragma unroll
  for (int tc = 0; tc < 2; ++tc)
#pragma unroll
    for (int r = 0; r < 4; ++r) cnr[tc * 4 + r] = cnS[tc * 16 + 4 * g + r];

  // ---- phase A: 4 passes x 128 nodes, pipelined MFMA scores + argmin ----
  for (int pass = 0; pass < 4; ++pass) {
    const int nodeloc = pass * 128 + w * 16 + l16;
    const float* xr = x + ((size_t)blockIdx.x * 512 + nodeloc) * HH;
    f4v acc[2];
    acc[0] = (f4v){0.f, 0.f, 0.f, 0.f};
    acc[1] = (f4v){0.f, 0.f, 0.f, 0.f};
    float4 pa[2][4], pb[2][4];
#pragma unroll
    for (int k = 0; k < 4; ++k) {              // prologue: chunk 0
      pa[0][k] = *(const float4*)&xr[k * 32 + g * 8];
      pb[0][k] = *(const float4*)&xr[k * 32 + g * 8 + 4];
    }
#pragma unroll
    for (int c4 = 0; c4 < 4; ++c4) {
      const int cur = c4 & 1, nxt = cur ^ 1;   // compile-time (unrolled)
      if (c4 < 3) {
#pragma unroll
        for (int k = 0; k < 4; ++k) {
          const int kk = (c4 + 1) * 4 + k;
          pa[nxt][k] = *(const float4*)&xr[kk * 32 + g * 8];
          pb[nxt][k] = *(const float4*)&xr[kk * 32 + g * 8 + 4];
        }
      }
#pragma unroll
      for (int k = 0; k < 4; ++k) {
        const int kk = c4 * 4 + k;
        float4 xa = pa[cur][k], xb = pb[cur][k];
        s8v bfrag;
        bfrag[0] = (short)f2bf(xa.x); bfrag[1] = (short)f2bf(xa.y);
        bfrag[2] = (short)f2bf(xa.z); bfrag[3] = (short)f2bf(xa.w);
        bfrag[4] = (short)f2bf(xb.x); bfrag[5] = (short)f2bf(xb.y);
        bfrag[6] = (short)f2bf(xb.z); bfrag[7] = (short)f2bf(xb.w);
#pragma unroll
        for (int tc = 0; tc < 2; ++tc) {
          s8v afrag = *(const s8v*)((unsigned char*)clbf +
                                    (tc * 16 + l16) * 1040 + kk * 64 + g * 16);
          acc[tc] = __builtin_amdgcn_mfma_f32_16x16x32_bf16(afrag, bfrag, acc[tc], 0, 0, 0);
        }
      }
    }
    // argmin (first-min on ties): in-lane ascending c order, then xor16/32
    float bv = 3.4e38f; int bi = 0;
#pragma unroll
    for (int tc = 0; tc < 2; ++tc)
#pragma unroll
      for (int r = 0; r < 4; ++r) {
        const int c = tc * 16 + 4 * g + r;
        const float v = cnr[tc * 4 + r] - 2.f * acc[tc][r];
        if (v < bv) { bv = v; bi = c; }
      }
#pragma unroll
    for (int m = 16; m <= 32; m <<= 1) {
      const float ov = __shfl_xor(bv, m);
      const int oi = __shfl_xor(bi, m);
      if (ov < bv || (ov == bv && oi < bi)) { bv = ov; bi = oi; }
    }
    if (l < 16) sa[nodeloc] = (unsigned char)bi;
  }
  __syncthreads();                     // clbf reads + sa writes done

  // ---- phase B: accumulate with 2-deep prefetch ----
  for (int i = tid; i < CC * HH; i += 512) buf[i] = 0.f;
  if (tid < CC) lc[tid] = 0.f;
  __syncthreads();

  const int wave = tid >> 6, lane = tid & 63;
  const int nb = blockIdx.x * 512 + wave * 64;
  {
    float v0[8], v1[8];
    int a0 = (int)sa[wave * 64], a1;
    {
      const float* xp = x + (size_t)nb * HH;
#pragma unroll
      for (int j = 0; j < 8; ++j) v0[j] = xp[j * 64 + lane];
    }
    for (int it = 0; it < 64; it += 2) {
      {
        a1 = (int)sa[wave * 64 + it + 1];
        const float* xp = x + (size_t)(nb + it + 1) * HH;
#pragma unroll
        for (int j = 0; j < 8; ++j) v1[j] = xp[j * 64 + lane];
      }
      if (lane == 0) atomicAdd(&lc[a0], 1.f);
#pragma unroll
      for (int j = 0; j < 8; ++j) atomicAdd(&buf[a0 * HH + j * 64 + lane], v0[j]);
      if (it + 2 < 64) {
        a0 = (int)sa[wave * 64 + it + 2];
        const float* xp = x + (size_t)(nb + it + 2) * HH;
#pragma unroll
        for (int j = 0; j < 8; ++j) v0[j] = xp[j * 64 + lane];
      }
      if (lane == 0) atomicAdd(&lc[a1], 1.f);
#pragma unroll
      for (int j = 0; j < 8; ++j) atomicAdd(&buf[a1 * HH + j * 64 + lane], v1[j]);
    }
  }
  __syncthreads();

  // ---- flush: 8 partial buffers + rotated start (de-convoy) ----
  const int pbuf = blockIdx.x & 7;
  const int rot = ((blockIdx.x >> 3) & 31) * 512;
  for (int i = tid; i < CC * HH; i += 512) {
    const int idx = (i + rot) & (CC * HH - 1);
    atomicAdd(&gsums[pbuf * 16384 + idx], buf[idx]);
  }
  if (tid < CC) atomicAdd(&gcounts[pbuf * 32 + tid], lc[tid]);
}

// ---------------------------------------------------------------------------
// Kernel 3: reduce 8 partials + EMA centroid update
// ---------------------------------------------------------------------------
__global__ void k_upd(const float* __restrict__ cent, const float* __restrict__ sums,
                      const float* __restrict__ counts, float* __restrict__ upd) {
  const int i = blockIdx.x * 256 + threadIdx.x;   // 16384
  const int c = i >> 9;
  float s = 0.f, cnt = 0.f;
#pragma unroll
  for (int b = 0; b < 8; ++b) { s += sums[b * 16384 + i]; cnt += counts[b * 32 + c]; }
  const float mean = s / fmaxf(cnt, 1.f);
  upd[i] = (cnt > 0.f) ? (MOMF * cent[i] + (1.f - MOMF) * mean) : cent[i];
}

// ---------------------------------------------------------------------------
// Kernel 4: k = upd@Wk + bk ; v = upd@Wv + bv   (32x512 each) — R2 exact
// ---------------------------------------------------------------------------
__global__ void k_kv(const float* __restrict__ upd,
                     const float* __restrict__ Wk, const float* __restrict__ bk,
                     const float* __restrict__ Wv, const float* __restrict__ bv,
                     float* __restrict__ kbuf, float* __restrict__ vbuf) {
  const int o = blockIdx.x * 256 + threadIdx.x;   // 0..32767
  const int sel = o >> 14;
  const int idx = o & 16383;
  const int c = idx >> 9, j = idx & 511;
  const float* W = sel ? Wv : Wk;
  const float* b = sel ? bv : bk;
  const float* u = upd + c * HH;
  float s = b[j];
  for (int i = 0; i < HH; ++i) s += u[i] * W[i * HH + j];
  (sel ? vbuf : kbuf)[idx] = s;
}

// ---------------------------------------------------------------------------
// Kernel 5: Mt (bf16, row-major transposed), sb, Pt (bf16, +bo/8) — R2 exact
// ---------------------------------------------------------------------------
__global__ void k_msp(const float* __restrict__ Wq, const float* __restrict__ bq,
                      const float* __restrict__ kbuf, const float* __restrict__ vbuf,
                      const float* __restrict__ Wo, const float* __restrict__ bo,
                      unsigned short* __restrict__ Mt, float* __restrict__ sb,
                      unsigned short* __restrict__ Pt) {
  const int b = blockIdx.x, t = threadIdx.x;
  const float scale = 0.125f;   // 1/sqrt(64)
  if (b < 512) {
    const int o = b * 256 + t;          // hc*512 + i
    const int hc = o >> 9, i = o & 511;
    const int h = hc >> 5, c = hc & 31;
    const float* wq = Wq + i * HH + h * 64;
    const float* kr = kbuf + c * HH + h * 64;
    float s = 0.f;
#pragma unroll
    for (int d = 0; d < 64; ++d) s += wq[d] * kr[d];
    Mt[o] = f2bf(s * scale);
  } else if (b < 1024) {
    const int o = b - 512;              // output col (0..511)
    const int hc = t;                   // 0..255
    const int h = hc >> 5, c = hc & 31;
    const float* vr = vbuf + c * HH + h * 64;
    const float* wo = Wo + h * 64 * HH + o;
    float s = 0.f;
#pragma unroll
    for (int d = 0; d < 64; ++d) s += vr[d] * wo[d * HH];
    Pt[o * 256 + hc] = f2bf(s + bo[o] * scale);
  } else if (t < 256) {
    const int h = t >> 5, c = t & 31;
    const float* kr = kbuf + c * HH + h * 64;
    const float* bqp = bq + h * 64;
    float s = 0.f;
#pragma unroll
    for (int d = 0; d < 64; ++d) s += bqp[d] * kr[d];
    sb[t] = s * scale;
  }
}

// ---------------------------------------------------------------------------
// Kernel 6 (main, MFMA): R6/R7 exact (LDS-staged A-frags, reg softmax/LN,
// windowed coalesced stores).
// ---------------------------------------------------------------------------
__global__ __launch_bounds__(256, 2) void k_main(
    const float* __restrict__ x, const unsigned short* __restrict__ Mt,
    const float* __restrict__ sb, const unsigned short* __restrict__ Pt,
    const float* __restrict__ lnw, const float* __restrict__ lnb,
    float* __restrict__ y) {
  __shared__ __align__(16) unsigned char smem[40960];  // stage / store window
  float* yb = (float*)smem;                            // [16][520] fp32 window
  const unsigned char* Mtb = (const unsigned char*)Mt;
  const unsigned char* Ptb = (const unsigned char*)Pt;
  const int tid = threadIdx.x;
  const int w = tid >> 6, l = tid & 63;
  const int l16 = l & 15, g = l >> 4;            // lane column / k-group
  const size_t n0 = (size_t)blockIdx.x * 64;
  const size_t xrow = n0 + w * 16 + l16;
  const float* xr = x + xrow * HH;

  // ---- phase 1: S^T[score_col=16tc+4g+r][xrow] ----
  f4v acc1[16];
#pragma unroll
  for (int tc = 0; tc < 16; ++tc)
    acc1[tc] = *(const f4v*)&sb[tc * 16 + 4 * g];

  for (int kk = 0; kk < 16; ++kk) {
    float4 xa = *(const float4*)&xr[kk * 32 + g * 8];
    float4 xb = *(const float4*)&xr[kk * 32 + g * 8 + 4];
    __syncthreads();                         // prev slice reads done
#pragma unroll
    for (int r = 0; r < 4; ++r)
      *(u4v*)(smem + tid * 80 + r * 16) =
          *(const u4v*)(Mtb + tid * 1024 + kk * 64 + r * 16);
    __syncthreads();                         // publish
    s8v bfrag;
    bfrag[0] = (short)f2bf(xa.x); bfrag[1] = (short)f2bf(xa.y);
    bfrag[2] = (short)f2bf(xa.z); bfrag[3] = (short)f2bf(xa.w);
    bfrag[4] = (short)f2bf(xb.x); bfrag[5] = (short)f2bf(xb.y);
    bfrag[6] = (short)f2bf(xb.z); bfrag[7] = (short)f2bf(xb.w);
#pragma unroll
    for (int tc = 0; tc < 16; ++tc) {
      s8v afrag = *(const s8v*)(smem + (tc * 16 + l16) * 80 + g * 16);
      acc1[tc] = __builtin_amdgcn_mfma_f32_16x16x32_bf16(afrag, bfrag, acc1[tc], 0, 0, 0);
    }
  }

  // ---- softmax per head h (cols 32h..32h+31): 8 in-lane + xor16/xor32 ----
  unsigned int apk[16][2];
#pragma unroll
  for (int h = 0; h < 8; ++h) {
    f4v s0 = acc1[2 * h], s1 = acc1[2 * h + 1];
    float m = fmaxf(fmaxf(fmaxf(s0[0], s0[1]), fmaxf(s0[2], s0[3])),
                    fmaxf(fmaxf(s1[0], s1[1]), fmaxf(s1[2], s1[3])));
    m = fmaxf(m, __shfl_xor(m, 16));
    m = fmaxf(m, __shfl_xor(m, 32));
    float e0 = __expf(s0[0] - m), e1 = __expf(s0[1] - m);
    float e2 = __expf(s0[2] - m), e3 = __expf(s0[3] - m);
    float e4 = __expf(s1[0] - m), e5 = __expf(s1[1] - m);
    float e6 = __expf(s1[2] - m), e7 = __expf(s1[3] - m);
    float sum = ((e0 + e1) + (e2 + e3)) + ((e4 + e5) + (e6 + e7));
    sum += __shfl_xor(sum, 16);
    sum += __shfl_xor(sum, 32);
    const float inv = 1.f / sum;
    apk[2 * h][0] = pk2bf(e0 * inv, e1 * inv);
    apk[2 * h][1] = pk2bf(e2 * inv, e3 * inv);
    apk[2 * h + 1][0] = pk2bf(e4 * inv, e5 * inv);
    apk[2 * h + 1][1] = pk2bf(e6 * inv, e7 * inv);
  }

  // ---- phase 2: C2^T[o=16to+4g+r][xrow] = sum_h Pt[o][32h..] attn^T ----
  f4v acc2[32];
#pragma unroll
  for (int to = 0; to < 32; ++to) acc2[to] = (f4v){0.f, 0.f, 0.f, 0.f};

  for (int h = 0; h < 8; ++h) {
    unsigned int dw[4];
#pragma unroll
    for (int d = 0; d < 4; ++d) {
      const int gsrc = 2 * (g & 1) + (d >> 1);
      const int src = l16 + 16 * gsrc;
      unsigned int t0 = (unsigned int)__shfl((int)apk[2 * h][d & 1], src, 64);
      unsigned int t1 = (unsigned int)__shfl((int)apk[2 * h + 1][d & 1], src, 64);
      dw[d] = (g < 2) ? t0 : t1;
    }
    u4v bu; bu[0] = dw[0]; bu[1] = dw[1]; bu[2] = dw[2]; bu[3] = dw[3];
    s8v bfrag = __builtin_bit_cast(s8v, bu);
    __syncthreads();                         // prev slice reads done
#pragma unroll
    for (int oo = 0; oo < 2; ++oo)
#pragma unroll
      for (int q = 0; q < 4; ++q)
        *(u4v*)(smem + (tid * 2 + oo) * 80 + q * 16) =
            *(const u4v*)(Ptb + (size_t)(tid * 2 + oo) * 512 + h * 64 + q * 16);
    __syncthreads();                         // publish
#pragma unroll
    for (int to = 0; to < 32; ++to) {
      s8v afrag = *(const s8v*)(smem + (to * 16 + l16) * 80 + g * 16);
      acc2[to] = __builtin_amdgcn_mfma_f32_16x16x32_bf16(afrag, bfrag, acc2[to], 0, 0, 0);
    }
  }

  // ---- epilogue: +residual (bo folded into Pt), LN in registers ----
  float s1 = 0.f, s2 = 0.f;
#pragma unroll
  for (int to = 0; to < 32; ++to) {
    float4 xv = *(const float4*)&xr[to * 16 + 4 * g];
    acc2[to][0] += xv.x; acc2[to][1] += xv.y;
    acc2[to][2] += xv.z; acc2[to][3] += xv.w;
    s1 += (acc2[to][0] + acc2[to][1]) + (acc2[to][2] + acc2[to][3]);
    s2 += (acc2[to][0] * acc2[to][0] + acc2[to][1] * acc2[to][1]) +
          (acc2[to][2] * acc2[to][2] + acc2[to][3] * acc2[to][3]);
  }
  s1 += __shfl_xor(s1, 16); s2 += __shfl_xor(s2, 16);
  s1 += __shfl_xor(s1, 32); s2 += __shfl_xor(s2, 32);
  const float mean = s1 * (1.f / 512.f);
  const float var = s2 * (1.f / 512.f) - mean * mean;
  const float rstd = rsqrtf(var + 1e-5f);
#pragma unroll
  for (int to = 0; to < 32; ++to) {
    float4 wv = *(const float4*)&lnw[to * 16 + 4 * g];
    float4 bv = *(const float4*)&lnb[to * 16 + 4 * g];
    acc2[to][0] = (acc2[to][0] - mean) * rstd * wv.x + bv.x;
    acc2[to][1] = (acc2[to][1] - mean) * rstd * wv.y + bv.y;
    acc2[to][2] = (acc2[to][2] - mean) * rstd * wv.z + bv.z;
    acc2[to][3] = (acc2[to][3] - mean) * rstd * wv.w + bv.w;
  }

  // ---- store via LDS windows (R5/R6 exact) ----
  const int prow = tid >> 7;               // 0..1
  const int pc = (tid & 127) * 4;          // float col within row
  for (int j = 0; j < 4; ++j) {
    __syncthreads();                       // window free / phase-2 reads done
    if (w == j) {
#pragma unroll
      for (int to = 0; to < 32; ++to)
        *(f4v*)&yb[l16 * 520 + to * 16 + 4 * g] = acc2[to];
    }
    __syncthreads();                       // publish
#pragma unroll
    for (int p = 0; p < 8; ++p)
      *(float4*)&y[(n0 + j * 16 + p * 2 + prow) * HH + pc] =
          *(const float4*)&yb[(p * 2 + prow) * 520 + pc];
  }
}

// ---------------------------------------------------------------------------
extern "C" void kernel_launch(void* const* d_in, const int* in_sizes, int n_in,
                              void* d_out, int out_size, void* d_ws, size_t ws_size,
                              hipStream_t stream) {
  const float* x    = (const float*)d_in[0];
  const float* cent = (const float*)d_in[1];
  const float* Wq   = (const float*)d_in[2];
  const float* bq   = (const float*)d_in[3];
  const float* Wk   = (const float*)d_in[4];
  const float* bk   = (const float*)d_in[5];
  const float* Wv   = (const float*)d_in[6];
  const float* bv   = (const float*)d_in[7];
  const float* Wo   = (const float*)d_in[8];
  const float* bo   = (const float*)d_in[9];
  const float* lnw  = (const float*)d_in[10];
  const float* lnb  = (const float*)d_in[11];
  float* ws = (float*)d_ws;
  float* y  = (float*)d_out;

  hipMemsetAsync(ws, 0, (8 * 16384 + 8 * 32) * sizeof(float), stream);
  k_km<<<512, 512, 0, stream>>>(x, cent, ws + WS_SUMS, ws + WS_COUNTS);
  k_upd<<<64, 256, 0, stream>>>(cent, ws + WS_SUMS, ws + WS_COUNTS, ws + WS_UPD);
  k_kv<<<128, 256, 0, stream>>>(ws + WS_UPD, Wk, bk, Wv, bv,
                                ws + WS_KBUF, ws + WS_VBUF);
  k_msp<<<1025, 256, 0, stream>>>(Wq, bq, ws + WS_KBUF, ws + WS_VBUF, Wo, bo,
                                  (unsigned short*)(ws + WS_MT), ws + WS_SB,
                                  (unsigned short*)(ws + WS_PT));
  k_main<<<4096, 256, 0, stream>>>(x, (const unsigned short*)(ws + WS_MT),
                                   ws + WS_SB, (const unsigned short*)(ws + WS_PT),
                                   lnw, lnb, y);
}